// Round 13
// baseline (106.760 us; speedup 1.0000x reference)
//
#include <hip/hip_runtime.h>

#define H_ 8
#define D_ 32
#define B_ 32
#define N_ 4096
#define C_ 256
#define EPS_ 1e-5f

// per-block partial slot: 1024 floats S + 32 floats T, padded to 1088
#define SLOT_ 1088

typedef __attribute__((ext_vector_type(8))) short bf16x8;
typedef __attribute__((ext_vector_type(4))) float f32x4;

__device__ __forceinline__ short f2bf(float f) {
    unsigned u = __builtin_bit_cast(unsigned, f);
    unsigned r = (u + 0x7FFFu + ((u >> 16) & 1u)) >> 16;
    return (short)r;
}
__device__ __forceinline__ float bf2f(short s) {
    return __builtin_bit_cast(float, ((unsigned)(unsigned short)s) << 16);
}

// physical short-index of (row, col) in ubuf: 80 B row stride + 32 B shift per
// 8-row group -> fragment reads conflict-free (verified R2: 0 conflicts).
__device__ __forceinline__ int uidx(int r, int c) {
    return r * 40 + ((r >> 3) & 3) * 16 + c;
}

// ---------------------------------------------------------------------------
// Kernel 1: per (b,h) accumulate S = U^T U and t = colsum(U) via MFMA
// (R6 hot loop byte-identical, ~16 µs), PLUS u (bf16) and (m,s) streamed out
// for k2 — but ALL stores DEFERRED to after the MFMA loop (held in regs),
// so the software-pipelined loop issues zero stores (R11's mistake undone).
// ---------------------------------------------------------------------------
__global__ __launch_bounds__(256, 3)
void k1_skv(const float* __restrict__ x, float* __restrict__ Pws,
            short* __restrict__ ug, float2* __restrict__ msg)
{
    __shared__ short ubuf[256 * 40 + 64];

    const int tid  = threadIdx.x;
    const int bh   = blockIdx.x >> 2;
    const int q4   = blockIdx.x & 3;
    const int b    = bh >> 3;
    const int h    = bh & 7;
    const int lane = tid & 63;
    const int wave = tid >> 6;
    const int g    = lane >> 4;
    const int cL   = lane & 15;

    f32x4 acc[2][2] = {};
    f32x4 tq[2] = {};

    bf16x8 uf[16];                   // deferred u fragments (4 iters x 4)
    float2 ms[4];                    // deferred (m, s) per iter

    bf16x8 ones;
    #pragma unroll
    for (int j = 0; j < 8; ++j) ones[j] = (short)0x3F80;

    const float* xbase = x + ((size_t)b * N_ + q4 * 1024 + tid) * C_ + h * D_;

    float4 xA[8], xB[8];
    #pragma unroll
    for (int c = 0; c < 8; ++c)
        xA[c] = reinterpret_cast<const float4*>(xbase)[c];

    auto body = [&](const float4 (&xr)[8], float4 (&nx)[8], int it, bool pf) {
        if (pf) {
            const float* p = xbase + (size_t)(it + 1) * 256 * C_;
            #pragma unroll
            for (int c = 0; c < 8; ++c)
                nx[c] = reinterpret_cast<const float4*>(p)[c];
        }

        float sum = 0.f, sq = 0.f;
        #pragma unroll
        for (int c = 0; c < 8; ++c) {
            const float4 a = xr[c];
            sum += a.x + a.y + a.z + a.w;
            sq = fmaf(a.x, a.x, fmaf(a.y, a.y, fmaf(a.z, a.z, fmaf(a.w, a.w, sq))));
        }
        const float m    = sum * (1.f / 32.f);
        const float ss   = fmaxf(sq - sum * m, 0.f);
        const float sdev = sqrtf(ss * (1.f / 31.f)) + EPS_;
        const float inv  = 1.0f / sdev;
        ms[it] = make_float2(m, sdev);

        {
            const int base = tid * 40 + ((tid >> 3) & 3) * 16;
            #pragma unroll
            for (int q = 0; q < 4; ++q) {
                const float4 a0 = xr[q * 2 + 0];
                const float4 a1 = xr[q * 2 + 1];
                bf16x8 wv;
                wv[0] = f2bf((a0.x - m) * inv); wv[1] = f2bf((a0.y - m) * inv);
                wv[2] = f2bf((a0.z - m) * inv); wv[3] = f2bf((a0.w - m) * inv);
                wv[4] = f2bf((a1.x - m) * inv); wv[5] = f2bf((a1.y - m) * inv);
                wv[6] = f2bf((a1.z - m) * inv); wv[7] = f2bf((a1.w - m) * inv);
                *reinterpret_cast<bf16x8*>(&ubuf[base + q * 8]) = wv;
                uf[it * 4 + q] = wv;            // register, not a store
            }
        }
        asm volatile("s_waitcnt lgkmcnt(0)" ::: "memory");

        #pragma unroll
        for (int ks = 0; ks < 2; ++ks) {
            const int R0 = wave * 64 + ks * 32 + 8 * g;
            bf16x8 F0, F1;
            #pragma unroll
            for (int j = 0; j < 8; ++j) {
                const int base = uidx(R0 + j, cL);
                F0[j] = ubuf[base];
                F1[j] = ubuf[base + 16];
            }
            tq[0] = __builtin_amdgcn_mfma_f32_16x16x32_bf16(ones, F0, tq[0], 0, 0, 0);
            tq[1] = __builtin_amdgcn_mfma_f32_16x16x32_bf16(ones, F1, tq[1], 0, 0, 0);
            acc[0][0] = __builtin_amdgcn_mfma_f32_16x16x32_bf16(F0, F0, acc[0][0], 0, 0, 0);
            acc[0][1] = __builtin_amdgcn_mfma_f32_16x16x32_bf16(F0, F1, acc[0][1], 0, 0, 0);
            acc[1][0] = __builtin_amdgcn_mfma_f32_16x16x32_bf16(F1, F0, acc[1][0], 0, 0, 0);
            acc[1][1] = __builtin_amdgcn_mfma_f32_16x16x32_bf16(F1, F1, acc[1][1], 0, 0, 0);
        }
    };

    body(xA, xB, 0, true);
    body(xB, xA, 1, true);
    body(xA, xB, 2, true);
    body(xB, xA, 3, false);

    // ---- deferred u + msg stores (one coalesced burst; latency overlaps
    //      the S epilogue below and other blocks' compute)
    #pragma unroll
    for (int it = 0; it < 4; ++it) {
        const size_t nrow = (size_t)bh * N_ + (size_t)q4 * 1024 + it * 256 + tid;
        short* up = ug + nrow * 32;
        #pragma unroll
        for (int q = 0; q < 4; ++q)
            *reinterpret_cast<bf16x8*>(up + q * 8) = uf[it * 4 + q];
        msg[nrow] = ms[it];
    }

    __syncthreads();
    float* sred = reinterpret_cast<float*>(ubuf);
    {
        float* dst = sred + wave * 1024;
        #pragma unroll
        for (int ca = 0; ca < 2; ++ca)
            #pragma unroll
            for (int cb = 0; cb < 2; ++cb)
                #pragma unroll
                for (int r = 0; r < 4; ++r)
                    dst[(ca * 16 + g * 4 + r) * D_ + cb * 16 + cL] = acc[ca][cb][r];
    }
    if (lane < 16) {
        sred[4096 + wave * 32 + cL]      = tq[0][0];
        sred[4096 + wave * 32 + 16 + cL] = tq[1][0];
    }
    __syncthreads();

    float* slot = Pws + (size_t)blockIdx.x * SLOT_;
    {
        const float4 c0 = *reinterpret_cast<const float4*>(&sred[tid * 4]);
        const float4 c1 = *reinterpret_cast<const float4*>(&sred[1024 + tid * 4]);
        const float4 c2 = *reinterpret_cast<const float4*>(&sred[2048 + tid * 4]);
        const float4 c3 = *reinterpret_cast<const float4*>(&sred[3072 + tid * 4]);
        float4 o;
        o.x = c0.x + c1.x + c2.x + c3.x;
        o.y = c0.y + c1.y + c2.y + c3.y;
        o.z = c0.z + c1.z + c2.z + c3.z;
        o.w = c0.w + c1.w + c2.w + c3.w;
        *reinterpret_cast<float4*>(slot + tid * 4) = o;
    }
    if (tid < D_)
        slot[1024 + tid] = sred[4096 + tid] + sred[4096 + 32 + tid]
                         + sred[4096 + 64 + tid] + sred[4096 + 96 + tid];
}

// ---------------------------------------------------------------------------
// Kernel 1b: reduce partial slots, fold weights/biases AND +I (residual) ->
// pre-packed bf16 hi+lo fragments + t' = colsum(kv').  (R11 verbatim)
// ---------------------------------------------------------------------------
__global__ __launch_bounds__(256, 4)
void k_red(const float* __restrict__ Pws,
           const float* __restrict__ kw, const float* __restrict__ kb,
           const float* __restrict__ vw, const float* __restrict__ vb,
           short* __restrict__ kvHi, short* __restrict__ kvLo,
           float* __restrict__ tp)
{
    __shared__ float kvm[1024];       // kv'[32][32]

    const int bh  = blockIdx.x;       // 0..255
    const int h   = bh & 7;
    const int tid = threadIdx.x;
    const int d   = tid >> 3;         // 0..31
    const int e0  = (tid & 7) * 4;    // 0,4,..,28

    const float* P0 = Pws + (size_t)(bh * 4 + 0) * SLOT_;
    const float* P1 = Pws + (size_t)(bh * 4 + 1) * SLOT_;
    const float* P2 = Pws + (size_t)(bh * 4 + 2) * SLOT_;
    const float* P3 = Pws + (size_t)(bh * 4 + 3) * SLOT_;
    const float invN = 1.f / (float)N_;

    const float4 s0 = *reinterpret_cast<const float4*>(P0 + d * D_ + e0);
    const float4 s1 = *reinterpret_cast<const float4*>(P1 + d * D_ + e0);
    const float4 s2 = *reinterpret_cast<const float4*>(P2 + d * D_ + e0);
    const float4 s3 = *reinterpret_cast<const float4*>(P3 + d * D_ + e0);
    float Sde[4] = { s0.x + s1.x + s2.x + s3.x, s0.y + s1.y + s2.y + s3.y,
                     s0.z + s1.z + s2.z + s3.z, s0.w + s1.w + s2.w + s3.w };

    const float Td  = P0[1024 + d] + P1[1024 + d] + P2[1024 + d] + P3[1024 + d];
    const float wkd = kw[h * D_ + d];
    const float bkd = kb[h * D_ + d];

    #pragma unroll
    for (int j = 0; j < 4; ++j) {
        const int e = e0 + j;
        const float Te  = P0[1024 + e] + P1[1024 + e] + P2[1024 + e] + P3[1024 + e];
        const float wve = vw[h * D_ + e];
        const float bve = vb[h * D_ + e];
        float v = invN * (wkd * (wve * Sde[j] + bve * Td) + bkd * wve * Te)
                + bkd * bve;
        if (d == e) v += 1.0f;                 // residual folded into kv'
        kvm[d * 32 + e] = v;
        const short hi = f2bf(v);
        const short lo = f2bf(v - bf2f(hi));
        const int hf  = e >> 4;
        const int l   = ((d >> 3) << 4) | (e & 15);
        const int idx = bh * 1024 + hf * 512 + l * 8 + (d & 7);
        kvHi[idx] = hi;
        kvLo[idx] = lo;
    }
    __syncthreads();
    if (tid < 32) {                            // t'[e] = sum_d kv'[d][e]
        float s = 0.f;
        #pragma unroll 8
        for (int dd = 0; dd < 32; ++dd) s += kvm[dd * 32 + tid];
        tp[bh * 32 + tid] = s;
    }
}

// ---------------------------------------------------------------------------
// Kernel 2: out[row] = s_h * (u . kv')_head + m_h * t'_head.  (R11 verbatim,
// verified, ~18 µs: reads bf16 u directly into the MFMA B-operand.)
// ---------------------------------------------------------------------------
__global__ __launch_bounds__(256, 4)
void k2_out(const short* __restrict__ ug, const float2* __restrict__ msg,
            const short* __restrict__ kvHi, const short* __restrict__ kvLo,
            const float* __restrict__ tp, float* __restrict__ out)
{
    __shared__ short kvL[16384];       // hi [0,8192), lo [8192,16384)
    __shared__ float tpL[256];

    const int tid  = threadIdx.x;
    const int lane = tid & 63;
    const int w    = tid >> 6;
    const int g    = lane >> 4;        // 0..3
    const int cL   = lane & 15;        // 0..15
    const int b    = blockIdx.x >> 6;  // 64 blocks per batch
    const int n    = (blockIdx.x & 63) * 64 + w * 16 + cL;   // row in batch

    // ---- fill kv'/t' LDS (L2-resident source), one barrier
    {
        const short* srcH = kvHi + (size_t)b * 8192;
        const short* srcL = kvLo + (size_t)b * 8192;
        #pragma unroll
        for (int i = 0; i < 4; ++i) {
            const int o = (tid + i * 256) * 8;
            *reinterpret_cast<bf16x8*>(&kvL[o]) =
                *reinterpret_cast<const bf16x8*>(srcH + o);
            *reinterpret_cast<bf16x8*>(&kvL[8192 + o]) =
                *reinterpret_cast<const bf16x8*>(srcL + o);
        }
        tpL[tid] = tp[b * 256 + tid];
    }

    // ---- issue this lane's u + (m,s) loads (independent of LDS fill)
    bf16x8 A[8];
    float2 ms[8];
    const short* up = ug + ((size_t)(b * 8) * N_ + n) * 32 + g * 8;
    #pragma unroll
    for (int h = 0; h < 8; ++h)
        A[h] = *reinterpret_cast<const bf16x8*>(up + (size_t)h * N_ * 32);
    #pragma unroll
    for (int h = 0; h < 8; ++h)
        ms[h] = msg[(size_t)(b * 8 + h) * N_ + n];

    __syncthreads();

    float* orow = out + ((size_t)b * N_ + n) * C_;
    const f32x4 zero = {0.f, 0.f, 0.f, 0.f};

    #pragma unroll
    for (int h = 0; h < 8; ++h) {
        #pragma unroll
        for (int hf = 0; hf < 2; ++hf) {
            const int si = h * 1024 + hf * 512 + lane * 8;
            const bf16x8 hi = *reinterpret_cast<const bf16x8*>(&kvL[si]);
            const bf16x8 lo = *reinterpret_cast<const bf16x8*>(&kvL[8192 + si]);
            f32x4 Dv;
            Dv = __builtin_amdgcn_mfma_f32_16x16x32_bf16(lo, A[h], zero, 0, 0, 0);
            Dv = __builtin_amdgcn_mfma_f32_16x16x32_bf16(hi, A[h], Dv,   0, 0, 0);
            const f32x4 t4 = *reinterpret_cast<const f32x4*>(&tpL[h * 32 + hf * 16 + 4 * g]);
            f32x4 o;
            #pragma unroll
            for (int c = 0; c < 4; ++c)
                o[c] = fmaf(ms[h].y, Dv[c], ms[h].x * t4[c]);
            *reinterpret_cast<f32x4*>(orow + h * 32 + hf * 16 + 4 * g) = o;
        }
    }
}

extern "C" void kernel_launch(void* const* d_in, const int* in_sizes, int n_in,
                              void* d_out, int out_size, void* d_ws, size_t ws_size,
                              hipStream_t stream)
{
    const float* x  = (const float*)d_in[0];
    const float* kw = (const float*)d_in[1];
    const float* kb = (const float*)d_in[2];
    const float* vw = (const float*)d_in[3];
    const float* vb = (const float*)d_in[4];
    float* outp = (float*)d_out;

    // workspace layout (16 B aligned chunks)
    float*  Pws  = (float*)d_ws;                               // 4.46 MB
    short*  kvHi = (short*)(Pws + (size_t)1024 * SLOT_);       // 512 KB
    short*  kvLo = kvHi + (size_t)256 * 1024;                  // 512 KB
    float*  tp   = (float*)(kvLo + (size_t)256 * 1024);        // 32 KB
    short*  ug   = (short*)(tp + (size_t)256 * 32);            // 64 MB (bf16 u)
    float2* msg  = (float2*)(ug + (size_t)256 * N_ * 32);      // 8 MB (m, s)

    k1_skv<<<dim3(B_ * H_ * 4), dim3(256), 0, stream>>>(x, Pws, ug, msg);
    k_red<<<dim3(B_ * H_), dim3(256), 0, stream>>>(Pws, kw, kb, vw, vb, kvHi, kvLo, tp);
    k2_out<<<dim3(B_ * N_ / 64), dim3(256), 0, stream>>>(ug, msg, kvHi, kvLo, tp, outp);
}

// Round 14
// 98.916 us; speedup vs baseline: 1.0793x; 1.0793x over previous
//
#include <hip/hip_runtime.h>

#define H_ 8
#define D_ 32
#define B_ 32
#define N_ 4096
#define C_ 256
#define EPS_ 1e-5f

// per-block partial slot: 1024 floats S + 32 floats T, padded to 1088
#define SLOT_ 1088

typedef __attribute__((ext_vector_type(8))) short bf16x8;
typedef __attribute__((ext_vector_type(4))) float f32x4;

__device__ __forceinline__ short f2bf(float f) {
    unsigned u = __builtin_bit_cast(unsigned, f);
    unsigned r = (u + 0x7FFFu + ((u >> 16) & 1u)) >> 16;
    return (short)r;
}
__device__ __forceinline__ float bf2f(short s) {
    return __builtin_bit_cast(float, ((unsigned)(unsigned short)s) << 16);
}

// physical short-index of (row, col) in ubuf: 80 B row stride + 32 B shift per
// 8-row group -> fragment reads conflict-free (verified R2: 0 conflicts).
__device__ __forceinline__ int uidx(int r, int c) {
    return r * 40 + ((r >> 3) & 3) * 16 + c;
}

// ---------------------------------------------------------------------------
// Kernel 1: per (b,h) accumulate S = U^T U and t = colsum(U) via MFMA
// (R6 hot-loop structure, 2 iters x 256 rows), streaming u (bf16) + (m,s).
// ALL u/msg stores are in ONE post-loop burst, pinned there by an asm memory
// fence (stores cannot hoist above it) — the hot loop issues ZERO stores.
// uf = 8 x bf16x8 = 32 VGPR held live; launch_bounds(256,3) avoids spill.
// u layout: ug[bh][q][n][8] -> store burst is lane-contiguous (dense 4 KB
// per wave-instruction); k2 reads one dense 16 B fragment per (h,row).
// ---------------------------------------------------------------------------
__global__ __launch_bounds__(256, 3)
void k1_skv(const float* __restrict__ x, float* __restrict__ Pws,
            short* __restrict__ ug, float2* __restrict__ msg)
{
    __shared__ short ubuf[256 * 40 + 64];

    const int tid  = threadIdx.x;
    const int bh   = blockIdx.x >> 3;
    const int q8   = blockIdx.x & 7;
    const int b    = bh >> 3;
    const int h    = bh & 7;
    const int lane = tid & 63;
    const int wave = tid >> 6;
    const int g    = lane >> 4;
    const int cL   = lane & 15;

    f32x4 acc[2][2] = {};
    f32x4 tq[2] = {};

    bf16x8 uf[8];                    // deferred u fragments (2 iters x 4)
    float2 ms[2];                    // deferred (m, s) per iter

    bf16x8 ones;
    #pragma unroll
    for (int j = 0; j < 8; ++j) ones[j] = (short)0x3F80;

    const float* xbase = x + ((size_t)b * N_ + q8 * 512 + tid) * C_ + h * D_;

    float4 xA[8], xB[8];
    #pragma unroll
    for (int c = 0; c < 8; ++c)
        xA[c] = reinterpret_cast<const float4*>(xbase)[c];

    auto body = [&](const float4 (&xr)[8], float4 (&nx)[8], int it, bool pf) {
        if (pf) {
            const float* p = xbase + (size_t)256 * C_;
            #pragma unroll
            for (int c = 0; c < 8; ++c)
                nx[c] = reinterpret_cast<const float4*>(p)[c];
        }

        float sum = 0.f, sq = 0.f;
        #pragma unroll
        for (int c = 0; c < 8; ++c) {
            const float4 a = xr[c];
            sum += a.x + a.y + a.z + a.w;
            sq = fmaf(a.x, a.x, fmaf(a.y, a.y, fmaf(a.z, a.z, fmaf(a.w, a.w, sq))));
        }
        const float m    = sum * (1.f / 32.f);
        const float ss   = fmaxf(sq - sum * m, 0.f);
        const float sdev = sqrtf(ss * (1.f / 31.f)) + EPS_;
        const float inv  = 1.0f / sdev;
        ms[it] = make_float2(m, sdev);

        {
            const int base = tid * 40 + ((tid >> 3) & 3) * 16;
            #pragma unroll
            for (int q = 0; q < 4; ++q) {
                const float4 a0 = xr[q * 2 + 0];
                const float4 a1 = xr[q * 2 + 1];
                bf16x8 wv;
                wv[0] = f2bf((a0.x - m) * inv); wv[1] = f2bf((a0.y - m) * inv);
                wv[2] = f2bf((a0.z - m) * inv); wv[3] = f2bf((a0.w - m) * inv);
                wv[4] = f2bf((a1.x - m) * inv); wv[5] = f2bf((a1.y - m) * inv);
                wv[6] = f2bf((a1.z - m) * inv); wv[7] = f2bf((a1.w - m) * inv);
                *reinterpret_cast<bf16x8*>(&ubuf[base + q * 8]) = wv;
                uf[it * 4 + q] = wv;            // held in registers
            }
        }
        asm volatile("s_waitcnt lgkmcnt(0)" ::: "memory");

        #pragma unroll
        for (int ks = 0; ks < 2; ++ks) {
            const int R0 = wave * 64 + ks * 32 + 8 * g;
            bf16x8 F0, F1;
            #pragma unroll
            for (int j = 0; j < 8; ++j) {
                const int base = uidx(R0 + j, cL);
                F0[j] = ubuf[base];
                F1[j] = ubuf[base + 16];
            }
            tq[0] = __builtin_amdgcn_mfma_f32_16x16x32_bf16(ones, F0, tq[0], 0, 0, 0);
            tq[1] = __builtin_amdgcn_mfma_f32_16x16x32_bf16(ones, F1, tq[1], 0, 0, 0);
            acc[0][0] = __builtin_amdgcn_mfma_f32_16x16x32_bf16(F0, F0, acc[0][0], 0, 0, 0);
            acc[0][1] = __builtin_amdgcn_mfma_f32_16x16x32_bf16(F0, F1, acc[0][1], 0, 0, 0);
            acc[1][0] = __builtin_amdgcn_mfma_f32_16x16x32_bf16(F1, F0, acc[1][0], 0, 0, 0);
            acc[1][1] = __builtin_amdgcn_mfma_f32_16x16x32_bf16(F1, F1, acc[1][1], 0, 0, 0);
        }
    };

    body(xA, xB, 0, true);
    body(xB, xA, 1, false);

    // ---- fence: stores below CANNOT be hoisted into the loop above
    asm volatile("" ::: "memory");

    // ---- one coalesced store burst (lane-contiguous per instruction)
    #pragma unroll
    for (int it = 0; it < 2; ++it) {
        const size_t r = (size_t)q8 * 512 + it * 256 + tid;
        #pragma unroll
        for (int q = 0; q < 4; ++q)
            *reinterpret_cast<bf16x8*>(
                ug + (((size_t)bh * 4 + q) * N_ + r) * 8) = uf[it * 4 + q];
        msg[(size_t)bh * N_ + r] = ms[it];
    }

    __syncthreads();
    float* sred = reinterpret_cast<float*>(ubuf);
    {
        float* dst = sred + wave * 1024;
        #pragma unroll
        for (int ca = 0; ca < 2; ++ca)
            #pragma unroll
            for (int cb = 0; cb < 2; ++cb)
                #pragma unroll
                for (int r = 0; r < 4; ++r)
                    dst[(ca * 16 + g * 4 + r) * D_ + cb * 16 + cL] = acc[ca][cb][r];
    }
    if (lane < 16) {
        sred[4096 + wave * 32 + cL]      = tq[0][0];
        sred[4096 + wave * 32 + 16 + cL] = tq[1][0];
    }
    __syncthreads();

    float* slot = Pws + (size_t)blockIdx.x * SLOT_;
    {
        const float4 c0 = *reinterpret_cast<const float4*>(&sred[tid * 4]);
        const float4 c1 = *reinterpret_cast<const float4*>(&sred[1024 + tid * 4]);
        const float4 c2 = *reinterpret_cast<const float4*>(&sred[2048 + tid * 4]);
        const float4 c3 = *reinterpret_cast<const float4*>(&sred[3072 + tid * 4]);
        float4 o;
        o.x = c0.x + c1.x + c2.x + c3.x;
        o.y = c0.y + c1.y + c2.y + c3.y;
        o.z = c0.z + c1.z + c2.z + c3.z;
        o.w = c0.w + c1.w + c2.w + c3.w;
        *reinterpret_cast<float4*>(slot + tid * 4) = o;
    }
    if (tid < D_)
        slot[1024 + tid] = sred[4096 + tid] + sred[4096 + 32 + tid]
                         + sred[4096 + 64 + tid] + sred[4096 + 96 + tid];
}

// ---------------------------------------------------------------------------
// Kernel 1b: reduce 8 partial slots, fold weights/biases AND +I (residual)
// -> pre-packed bf16 hi+lo fragments + t' = colsum(kv').
// ---------------------------------------------------------------------------
__global__ __launch_bounds__(256, 4)
void k_red(const float* __restrict__ Pws,
           const float* __restrict__ kw, const float* __restrict__ kb,
           const float* __restrict__ vw, const float* __restrict__ vb,
           short* __restrict__ kvHi, short* __restrict__ kvLo,
           float* __restrict__ tp)
{
    __shared__ float kvm[1024];       // kv'[32][32]

    const int bh  = blockIdx.x;       // 0..255
    const int h   = bh & 7;
    const int tid = threadIdx.x;
    const int d   = tid >> 3;         // 0..31
    const int e0  = (tid & 7) * 4;    // 0,4,..,28

    const float* P[8];
    #pragma unroll
    for (int s = 0; s < 8; ++s)
        P[s] = Pws + (size_t)(bh * 8 + s) * SLOT_;
    const float invN = 1.f / (float)N_;

    float Sde[4] = {0.f, 0.f, 0.f, 0.f};
    float Td = 0.f;
    #pragma unroll
    for (int s = 0; s < 8; ++s) {
        const float4 sv = *reinterpret_cast<const float4*>(P[s] + d * D_ + e0);
        Sde[0] += sv.x; Sde[1] += sv.y; Sde[2] += sv.z; Sde[3] += sv.w;
        Td += P[s][1024 + d];
    }

    const float wkd = kw[h * D_ + d];
    const float bkd = kb[h * D_ + d];

    #pragma unroll
    for (int j = 0; j < 4; ++j) {
        const int e = e0 + j;
        float Te = 0.f;
        #pragma unroll
        for (int s = 0; s < 8; ++s) Te += P[s][1024 + e];
        const float wve = vw[h * D_ + e];
        const float bve = vb[h * D_ + e];
        float v = invN * (wkd * (wve * Sde[j] + bve * Td) + bkd * wve * Te)
                + bkd * bve;
        if (d == e) v += 1.0f;                 // residual folded into kv'
        kvm[d * 32 + e] = v;
        const short hi = f2bf(v);
        const short lo = f2bf(v - bf2f(hi));
        const int hf  = e >> 4;
        const int l   = ((d >> 3) << 4) | (e & 15);
        const int idx = bh * 1024 + hf * 512 + l * 8 + (d & 7);
        kvHi[idx] = hi;
        kvLo[idx] = lo;
    }
    __syncthreads();
    if (tid < 32) {                            // t'[e] = sum_d kv'[d][e]
        float s = 0.f;
        #pragma unroll 8
        for (int dd = 0; dd < 32; ++dd) s += kvm[dd * 32 + tid];
        tp[bh * 32 + tid] = s;
    }
}

// ---------------------------------------------------------------------------
// Kernel 2: out[row] = s_h * (u . kv')_head + m_h * t'_head.  (R11/R13
// verified structure, ~18 µs; only the ug addressing reflects the new
// [bh][q][n][8] layout — one dense 16 B fragment per (h,row).)
// ---------------------------------------------------------------------------
__global__ __launch_bounds__(256, 4)
void k2_out(const short* __restrict__ ug, const float2* __restrict__ msg,
            const short* __restrict__ kvHi, const short* __restrict__ kvLo,
            const float* __restrict__ tp, float* __restrict__ out)
{
    __shared__ short kvL[16384];       // hi [0,8192), lo [8192,16384)
    __shared__ float tpL[256];

    const int tid  = threadIdx.x;
    const int lane = tid & 63;
    const int w    = tid >> 6;
    const int g    = lane >> 4;        // 0..3
    const int cL   = lane & 15;        // 0..15
    const int b    = blockIdx.x >> 6;  // 64 blocks per batch
    const int n    = (blockIdx.x & 63) * 64 + w * 16 + cL;   // row in batch

    // ---- fill kv'/t' LDS (L2-resident source), one barrier
    {
        const short* srcH = kvHi + (size_t)b * 8192;
        const short* srcL = kvLo + (size_t)b * 8192;
        #pragma unroll
        for (int i = 0; i < 4; ++i) {
            const int o = (tid + i * 256) * 8;
            *reinterpret_cast<bf16x8*>(&kvL[o]) =
                *reinterpret_cast<const bf16x8*>(srcH + o);
            *reinterpret_cast<bf16x8*>(&kvL[8192 + o]) =
                *reinterpret_cast<const bf16x8*>(srcL + o);
        }
        tpL[tid] = tp[b * 256 + tid];
    }

    // ---- issue this lane's u + (m,s) loads (independent of LDS fill)
    bf16x8 A[8];
    float2 ms[8];
    #pragma unroll
    for (int h = 0; h < 8; ++h)
        A[h] = *reinterpret_cast<const bf16x8*>(
            ug + (((size_t)(b * 8 + h) * 4 + g) * N_ + n) * 8);
    #pragma unroll
    for (int h = 0; h < 8; ++h)
        ms[h] = msg[(size_t)(b * 8 + h) * N_ + n];

    __syncthreads();

    float* orow = out + ((size_t)b * N_ + n) * C_;
    const f32x4 zero = {0.f, 0.f, 0.f, 0.f};

    #pragma unroll
    for (int h = 0; h < 8; ++h) {
        #pragma unroll
        for (int hf = 0; hf < 2; ++hf) {
            const int si = h * 1024 + hf * 512 + lane * 8;
            const bf16x8 hi = *reinterpret_cast<const bf16x8*>(&kvL[si]);
            const bf16x8 lo = *reinterpret_cast<const bf16x8*>(&kvL[8192 + si]);
            f32x4 Dv;
            Dv = __builtin_amdgcn_mfma_f32_16x16x32_bf16(lo, A[h], zero, 0, 0, 0);
            Dv = __builtin_amdgcn_mfma_f32_16x16x32_bf16(hi, A[h], Dv,   0, 0, 0);
            const f32x4 t4 = *reinterpret_cast<const f32x4*>(&tpL[h * 32 + hf * 16 + 4 * g]);
            f32x4 o;
            #pragma unroll
            for (int c = 0; c < 4; ++c)
                o[c] = fmaf(ms[h].y, Dv[c], ms[h].x * t4[c]);
            *reinterpret_cast<f32x4*>(orow + h * 32 + hf * 16 + 4 * g) = o;
        }
    }
}

extern "C" void kernel_launch(void* const* d_in, const int* in_sizes, int n_in,
                              void* d_out, int out_size, void* d_ws, size_t ws_size,
                              hipStream_t stream)
{
    const float* x  = (const float*)d_in[0];
    const float* kw = (const float*)d_in[1];
    const float* kb = (const float*)d_in[2];
    const float* vw = (const float*)d_in[3];
    const float* vb = (const float*)d_in[4];
    float* outp = (float*)d_out;

    // workspace layout (16 B aligned chunks)
    float*  Pws  = (float*)d_ws;                               // 2048 x 1088 f (8.9 MB)
    short*  kvHi = (short*)(Pws + (size_t)2048 * SLOT_);       // 512 KB
    short*  kvLo = kvHi + (size_t)256 * 1024;                  // 512 KB
    float*  tp   = (float*)(kvLo + (size_t)256 * 1024);        // 32 KB
    short*  ug   = (short*)(tp + (size_t)256 * 32);            // 64 MB (bf16 u)
    float2* msg  = (float2*)(ug + (size_t)256 * N_ * 32);      // 8 MB (m, s)

    k1_skv<<<dim3(B_ * H_ * 8), dim3(256), 0, stream>>>(x, Pws, ug, msg);
    k_red<<<dim3(B_ * H_), dim3(256), 0, stream>>>(Pws, kw, kb, vw, vb, kvHi, kvLo, tp);
    k2_out<<<dim3(B_ * N_ / 64), dim3(256), 0, stream>>>(ug, msg, kvHi, kvLo, tp, outp);
}

// Round 15
// 84.117 us; speedup vs baseline: 1.2692x; 1.1759x over previous
//
#include <hip/hip_runtime.h>

#define H_ 8
#define D_ 32
#define B_ 32
#define N_ 4096
#define C_ 256
#define EPS_ 1e-5f

// per-block partial slot: 1024 floats S + 32 floats T, padded to 1088
#define SLOT_ 1088

typedef __attribute__((ext_vector_type(8))) short bf16x8;
typedef __attribute__((ext_vector_type(4))) float f32x4;

__device__ __forceinline__ short f2bf(float f) {
    unsigned u = __builtin_bit_cast(unsigned, f);
    unsigned r = (u + 0x7FFFu + ((u >> 16) & 1u)) >> 16;
    return (short)r;
}

// physical short-index of (row, col) in ubuf: 80 B row stride + 32 B shift per
// 8-row group -> fragment reads conflict-free (verified R2: 0 conflicts).
__device__ __forceinline__ int uidx(int r, int c) {
    return r * 40 + ((r >> 3) & 3) * 16 + c;
}

// ---------------------------------------------------------------------------
// Kernel 1: per (b,h) accumulate S = U^T U (32x32) and t = colsum(U) via MFMA.
// R6/R12 version VERBATIM (measured ~16 µs): 1024 blocks x 4 software-
// pipelined 256-row iters, wave-private LDS stripes, zero hot-loop barriers,
// no atomics, per-block partial slots.
// ---------------------------------------------------------------------------
__global__ __launch_bounds__(256, 4)
void k1_skv(const float* __restrict__ x, float* __restrict__ Pws)
{
    __shared__ short ubuf[256 * 40 + 64];

    const int tid  = threadIdx.x;
    const int bh   = blockIdx.x >> 2;
    const int q4   = blockIdx.x & 3;
    const int b    = bh >> 3;
    const int h    = bh & 7;
    const int lane = tid & 63;
    const int wave = tid >> 6;
    const int g    = lane >> 4;
    const int cL   = lane & 15;

    f32x4 acc[2][2] = {};
    f32x4 tq[2] = {};

    bf16x8 ones;
    #pragma unroll
    for (int j = 0; j < 8; ++j) ones[j] = (short)0x3F80;

    const float* xbase = x + ((size_t)b * N_ + q4 * 1024 + tid) * C_ + h * D_;

    float4 xA[8], xB[8];
    #pragma unroll
    for (int c = 0; c < 8; ++c)
        xA[c] = reinterpret_cast<const float4*>(xbase)[c];

    auto body = [&](const float4 (&xr)[8], float4 (&nx)[8], int it, bool pf) {
        if (pf) {
            const float* p = xbase + (size_t)(it + 1) * 256 * C_;
            #pragma unroll
            for (int c = 0; c < 8; ++c)
                nx[c] = reinterpret_cast<const float4*>(p)[c];
        }

        float sum = 0.f, sq = 0.f;
        #pragma unroll
        for (int c = 0; c < 8; ++c) {
            const float4 a = xr[c];
            sum += a.x + a.y + a.z + a.w;
            sq = fmaf(a.x, a.x, fmaf(a.y, a.y, fmaf(a.z, a.z, fmaf(a.w, a.w, sq))));
        }
        const float m   = sum * (1.f / 32.f);
        const float ss  = fmaxf(sq - sum * m, 0.f);
        const float inv = 1.f / (sqrtf(ss * (1.f / 31.f)) + EPS_);

        {
            const int base = tid * 40 + ((tid >> 3) & 3) * 16;
            #pragma unroll
            for (int q = 0; q < 4; ++q) {
                const float4 a0 = xr[q * 2 + 0];
                const float4 a1 = xr[q * 2 + 1];
                bf16x8 wv;
                wv[0] = f2bf((a0.x - m) * inv); wv[1] = f2bf((a0.y - m) * inv);
                wv[2] = f2bf((a0.z - m) * inv); wv[3] = f2bf((a0.w - m) * inv);
                wv[4] = f2bf((a1.x - m) * inv); wv[5] = f2bf((a1.y - m) * inv);
                wv[6] = f2bf((a1.z - m) * inv); wv[7] = f2bf((a1.w - m) * inv);
                *reinterpret_cast<bf16x8*>(&ubuf[base + q * 8]) = wv;
            }
        }
        asm volatile("s_waitcnt lgkmcnt(0)" ::: "memory");

        #pragma unroll
        for (int ks = 0; ks < 2; ++ks) {
            const int R0 = wave * 64 + ks * 32 + 8 * g;
            bf16x8 F0, F1;
            #pragma unroll
            for (int j = 0; j < 8; ++j) {
                const int base = uidx(R0 + j, cL);
                F0[j] = ubuf[base];
                F1[j] = ubuf[base + 16];
            }
            tq[0] = __builtin_amdgcn_mfma_f32_16x16x32_bf16(ones, F0, tq[0], 0, 0, 0);
            tq[1] = __builtin_amdgcn_mfma_f32_16x16x32_bf16(ones, F1, tq[1], 0, 0, 0);
            acc[0][0] = __builtin_amdgcn_mfma_f32_16x16x32_bf16(F0, F0, acc[0][0], 0, 0, 0);
            acc[0][1] = __builtin_amdgcn_mfma_f32_16x16x32_bf16(F0, F1, acc[0][1], 0, 0, 0);
            acc[1][0] = __builtin_amdgcn_mfma_f32_16x16x32_bf16(F1, F0, acc[1][0], 0, 0, 0);
            acc[1][1] = __builtin_amdgcn_mfma_f32_16x16x32_bf16(F1, F1, acc[1][1], 0, 0, 0);
        }
    };

    body(xA, xB, 0, true);
    body(xB, xA, 1, true);
    body(xA, xB, 2, true);
    body(xB, xA, 3, false);

    __syncthreads();
    float* sred = reinterpret_cast<float*>(ubuf);
    {
        float* dst = sred + wave * 1024;
        #pragma unroll
        for (int ca = 0; ca < 2; ++ca)
            #pragma unroll
            for (int cb = 0; cb < 2; ++cb)
                #pragma unroll
                for (int r = 0; r < 4; ++r)
                    dst[(ca * 16 + g * 4 + r) * D_ + cb * 16 + cL] = acc[ca][cb][r];
    }
    if (lane < 16) {
        sred[4096 + wave * 32 + cL]      = tq[0][0];
        sred[4096 + wave * 32 + 16 + cL] = tq[1][0];
    }
    __syncthreads();

    float* slot = Pws + (size_t)blockIdx.x * SLOT_;
    {
        const float4 c0 = *reinterpret_cast<const float4*>(&sred[tid * 4]);
        const float4 c1 = *reinterpret_cast<const float4*>(&sred[1024 + tid * 4]);
        const float4 c2 = *reinterpret_cast<const float4*>(&sred[2048 + tid * 4]);
        const float4 c3 = *reinterpret_cast<const float4*>(&sred[3072 + tid * 4]);
        float4 o;
        o.x = c0.x + c1.x + c2.x + c3.x;
        o.y = c0.y + c1.y + c2.y + c3.y;
        o.z = c0.z + c1.z + c2.z + c3.z;
        o.w = c0.w + c1.w + c2.w + c3.w;
        *reinterpret_cast<float4*>(slot + tid * 4) = o;
    }
    if (tid < D_)
        slot[1024 + tid] = sred[4096 + tid] + sred[4096 + 32 + tid]
                         + sred[4096 + 64 + tid] + sred[4096 + 96 + tid];
}

// ---------------------------------------------------------------------------
// Kernel 1b: reduce the 4 partial slots + fold weights/biases AND the
// residual identity (kv' = kv + I) into the FINAL fp32 kvF[bh][d][e].
// (R12 verbatim)
// ---------------------------------------------------------------------------
__global__ __launch_bounds__(256, 4)
void k_red(const float* __restrict__ Pws,
           const float* __restrict__ kw, const float* __restrict__ kb,
           const float* __restrict__ vw, const float* __restrict__ vb,
           float* __restrict__ kvF)
{
    const int bh  = blockIdx.x;       // 0..255
    const int h   = bh & 7;
    const int tid = threadIdx.x;
    const int d   = tid >> 3;         // 0..31
    const int e0  = (tid & 7) * 4;    // 0,4,..,28

    const float* P0 = Pws + (size_t)(bh * 4 + 0) * SLOT_;
    const float* P1 = Pws + (size_t)(bh * 4 + 1) * SLOT_;
    const float* P2 = Pws + (size_t)(bh * 4 + 2) * SLOT_;
    const float* P3 = Pws + (size_t)(bh * 4 + 3) * SLOT_;
    const float invN = 1.f / (float)N_;

    const float4 s0 = *reinterpret_cast<const float4*>(P0 + d * D_ + e0);
    const float4 s1 = *reinterpret_cast<const float4*>(P1 + d * D_ + e0);
    const float4 s2 = *reinterpret_cast<const float4*>(P2 + d * D_ + e0);
    const float4 s3 = *reinterpret_cast<const float4*>(P3 + d * D_ + e0);
    float Sde[4] = { s0.x + s1.x + s2.x + s3.x, s0.y + s1.y + s2.y + s3.y,
                     s0.z + s1.z + s2.z + s3.z, s0.w + s1.w + s2.w + s3.w };

    const float Td  = P0[1024 + d] + P1[1024 + d] + P2[1024 + d] + P3[1024 + d];
    const float wkd = kw[h * D_ + d];
    const float bkd = kb[h * D_ + d];

    float4 o;
    float* op = &o.x;
    #pragma unroll
    for (int j = 0; j < 4; ++j) {
        const int e = e0 + j;
        const float Te  = P0[1024 + e] + P1[1024 + e] + P2[1024 + e] + P3[1024 + e];
        const float wve = vw[h * D_ + e];
        const float bve = vb[h * D_ + e];
        float v = invN * (wkd * (wve * Sde[j] + bve * Td) + bkd * wve * Te)
                + bkd * bve;
        if (d == e) v += 1.0f;                 // residual folded into kv'
        op[j] = v;
    }
    *reinterpret_cast<float4*>(kvF + (size_t)bh * 1024 + d * D_ + e0) = o;
}

// ---------------------------------------------------------------------------
// Kernel 2: out[b,n,c] = sum_d x[b,n,h*32+d] * kv'[b,h][d][e]  (residual
// inside kv'). R12 structure with exactly two changes:
//  (1) REVERSED row order within each batch -> consume k1's L3-warm tail of
//      x first, before our own writes evict it;
//  (2) NONTEMPORAL out stores -> the 128 MB write stream (never re-read)
//      bypasses L2/L3 instead of evicting x.
// ---------------------------------------------------------------------------
__global__ __launch_bounds__(256, 4)
void k2_out(const float* __restrict__ x, const float* __restrict__ kvF,
            float* __restrict__ out)
{
    __shared__ float xbuf[4 * C_];     // 4 rows staged, 4 KB

    const int tid   = threadIdx.x;
    const int b     = blockIdx.x >> 6;
    const int chunk = 63 - (blockIdx.x & 63);   // (1) reverse within batch
    const int h     = tid >> 5;
    const int e     = tid & 31;
    const int bh    = b * 8 + h;

    // kv' column e for head h, in registers (L2-resident kvF)
    const float* kvp = kvF + (size_t)bh * 1024 + e;
    float kvc[32];
    #pragma unroll
    for (int d = 0; d < D_; ++d) kvc[d] = kvp[d * D_];

    for (int it = 15; it >= 0; --it) {          // (1) reverse within block
        const int r0 = chunk * 64 + it * 4;
        const float* xrow = x + ((size_t)b * N_ + r0) * C_;
        const float4 xv = reinterpret_cast<const float4*>(xrow)[tid]; // 4 rows coalesced
        __syncthreads();                       // protect previous iter's reads
        reinterpret_cast<float4*>(xbuf)[tid] = xv;
        __syncthreads();

        float res[4];
        #pragma unroll
        for (int r = 0; r < 4; ++r) {
            const float4* xr4 = reinterpret_cast<const float4*>(xbuf + r * C_ + h * D_);
            float dot = 0.f;
            #pragma unroll
            for (int c = 0; c < 8; ++c) {
                const float4 a = xr4[c];
                dot += a.x * kvc[c * 4 + 0] + a.y * kvc[c * 4 + 1]
                     + a.z * kvc[c * 4 + 2] + a.w * kvc[c * 4 + 3];
            }
            res[r] = dot;                      // residual folded into kv'
        }
        float* orow = out + ((size_t)b * N_ + r0) * C_;
        #pragma unroll
        for (int r = 0; r < 4; ++r)
            __builtin_nontemporal_store(res[r], orow + r * C_ + tid);  // (2)
    }
}

extern "C" void kernel_launch(void* const* d_in, const int* in_sizes, int n_in,
                              void* d_out, int out_size, void* d_ws, size_t ws_size,
                              hipStream_t stream)
{
    const float* x  = (const float*)d_in[0];
    const float* kw = (const float*)d_in[1];
    const float* kb = (const float*)d_in[2];
    const float* vw = (const float*)d_in[3];
    const float* vb = (const float*)d_in[4];
    float* outp = (float*)d_out;

    float* Pws = (float*)d_ws;                       // 1024 x 1088 floats (4.46 MB)
    float* kvF = Pws + (size_t)1024 * SLOT_;         // 256 x 1024 floats (1 MB)

    k1_skv<<<dim3(B_ * H_ * 4), dim3(256), 0, stream>>>(x, Pws);
    k_red<<<dim3(B_ * H_), dim3(256), 0, stream>>>(Pws, kw, kb, vw, vb, kvF);
    k2_out<<<dim3(B_ * 64), dim3(256), 0, stream>>>(x, kvF, outp);
}

// Round 16
// 83.246 us; speedup vs baseline: 1.2825x; 1.0105x over previous
//
#include <hip/hip_runtime.h>

#define H_ 8
#define D_ 32
#define B_ 32
#define N_ 4096
#define C_ 256
#define EPS_ 1e-5f

// per-block partial slot: 1024 floats S + 32 floats T, padded to 1088
#define SLOT_ 1088

typedef __attribute__((ext_vector_type(8))) short bf16x8;
typedef __attribute__((ext_vector_type(4))) float f32x4;

__device__ __forceinline__ short f2bf(float f) {
    unsigned u = __builtin_bit_cast(unsigned, f);
    unsigned r = (u + 0x7FFFu + ((u >> 16) & 1u)) >> 16;
    return (short)r;
}

// physical short-index of (row, col) in ubuf: 80 B row stride + 32 B shift per
// 8-row group -> fragment reads conflict-free (verified R2: 0 conflicts).
__device__ __forceinline__ int uidx(int r, int c) {
    return r * 40 + ((r >> 3) & 3) * 16 + c;
}

// ---------------------------------------------------------------------------
// Kernel 1: per (b,h) accumulate S = U^T U (32x32) and t = colsum(U) via MFMA.
// R6/R12 version VERBATIM (measured ~16 µs).
// ---------------------------------------------------------------------------
__global__ __launch_bounds__(256, 4)
void k1_skv(const float* __restrict__ x, float* __restrict__ Pws)
{
    __shared__ short ubuf[256 * 40 + 64];

    const int tid  = threadIdx.x;
    const int bh   = blockIdx.x >> 2;
    const int q4   = blockIdx.x & 3;
    const int b    = bh >> 3;
    const int h    = bh & 7;
    const int lane = tid & 63;
    const int wave = tid >> 6;
    const int g    = lane >> 4;
    const int cL   = lane & 15;

    f32x4 acc[2][2] = {};
    f32x4 tq[2] = {};

    bf16x8 ones;
    #pragma unroll
    for (int j = 0; j < 8; ++j) ones[j] = (short)0x3F80;

    const float* xbase = x + ((size_t)b * N_ + q4 * 1024 + tid) * C_ + h * D_;

    float4 xA[8], xB[8];
    #pragma unroll
    for (int c = 0; c < 8; ++c)
        xA[c] = reinterpret_cast<const float4*>(xbase)[c];

    auto body = [&](const float4 (&xr)[8], float4 (&nx)[8], int it, bool pf) {
        if (pf) {
            const float* p = xbase + (size_t)(it + 1) * 256 * C_;
            #pragma unroll
            for (int c = 0; c < 8; ++c)
                nx[c] = reinterpret_cast<const float4*>(p)[c];
        }

        float sum = 0.f, sq = 0.f;
        #pragma unroll
        for (int c = 0; c < 8; ++c) {
            const float4 a = xr[c];
            sum += a.x + a.y + a.z + a.w;
            sq = fmaf(a.x, a.x, fmaf(a.y, a.y, fmaf(a.z, a.z, fmaf(a.w, a.w, sq))));
        }
        const float m   = sum * (1.f / 32.f);
        const float ss  = fmaxf(sq - sum * m, 0.f);
        const float inv = 1.f / (sqrtf(ss * (1.f / 31.f)) + EPS_);

        {
            const int base = tid * 40 + ((tid >> 3) & 3) * 16;
            #pragma unroll
            for (int q = 0; q < 4; ++q) {
                const float4 a0 = xr[q * 2 + 0];
                const float4 a1 = xr[q * 2 + 1];
                bf16x8 wv;
                wv[0] = f2bf((a0.x - m) * inv); wv[1] = f2bf((a0.y - m) * inv);
                wv[2] = f2bf((a0.z - m) * inv); wv[3] = f2bf((a0.w - m) * inv);
                wv[4] = f2bf((a1.x - m) * inv); wv[5] = f2bf((a1.y - m) * inv);
                wv[6] = f2bf((a1.z - m) * inv); wv[7] = f2bf((a1.w - m) * inv);
                *reinterpret_cast<bf16x8*>(&ubuf[base + q * 8]) = wv;
            }
        }
        asm volatile("s_waitcnt lgkmcnt(0)" ::: "memory");

        #pragma unroll
        for (int ks = 0; ks < 2; ++ks) {
            const int R0 = wave * 64 + ks * 32 + 8 * g;
            bf16x8 F0, F1;
            #pragma unroll
            for (int j = 0; j < 8; ++j) {
                const int base = uidx(R0 + j, cL);
                F0[j] = ubuf[base];
                F1[j] = ubuf[base + 16];
            }
            tq[0] = __builtin_amdgcn_mfma_f32_16x16x32_bf16(ones, F0, tq[0], 0, 0, 0);
            tq[1] = __builtin_amdgcn_mfma_f32_16x16x32_bf16(ones, F1, tq[1], 0, 0, 0);
            acc[0][0] = __builtin_amdgcn_mfma_f32_16x16x32_bf16(F0, F0, acc[0][0], 0, 0, 0);
            acc[0][1] = __builtin_amdgcn_mfma_f32_16x16x32_bf16(F0, F1, acc[0][1], 0, 0, 0);
            acc[1][0] = __builtin_amdgcn_mfma_f32_16x16x32_bf16(F1, F0, acc[1][0], 0, 0, 0);
            acc[1][1] = __builtin_amdgcn_mfma_f32_16x16x32_bf16(F1, F1, acc[1][1], 0, 0, 0);
        }
    };

    body(xA, xB, 0, true);
    body(xB, xA, 1, true);
    body(xA, xB, 2, true);
    body(xB, xA, 3, false);

    __syncthreads();
    float* sred = reinterpret_cast<float*>(ubuf);
    {
        float* dst = sred + wave * 1024;
        #pragma unroll
        for (int ca = 0; ca < 2; ++ca)
            #pragma unroll
            for (int cb = 0; cb < 2; ++cb)
                #pragma unroll
                for (int r = 0; r < 4; ++r)
                    dst[(ca * 16 + g * 4 + r) * D_ + cb * 16 + cL] = acc[ca][cb][r];
    }
    if (lane < 16) {
        sred[4096 + wave * 32 + cL]      = tq[0][0];
        sred[4096 + wave * 32 + 16 + cL] = tq[1][0];
    }
    __syncthreads();

    float* slot = Pws + (size_t)blockIdx.x * SLOT_;
    {
        const float4 c0 = *reinterpret_cast<const float4*>(&sred[tid * 4]);
        const float4 c1 = *reinterpret_cast<const float4*>(&sred[1024 + tid * 4]);
        const float4 c2 = *reinterpret_cast<const float4*>(&sred[2048 + tid * 4]);
        const float4 c3 = *reinterpret_cast<const float4*>(&sred[3072 + tid * 4]);
        float4 o;
        o.x = c0.x + c1.x + c2.x + c3.x;
        o.y = c0.y + c1.y + c2.y + c3.y;
        o.z = c0.z + c1.z + c2.z + c3.z;
        o.w = c0.w + c1.w + c2.w + c3.w;
        *reinterpret_cast<float4*>(slot + tid * 4) = o;
    }
    if (tid < D_)
        slot[1024 + tid] = sred[4096 + tid] + sred[4096 + 32 + tid]
                         + sred[4096 + 64 + tid] + sred[4096 + 96 + tid];
}

// ---------------------------------------------------------------------------
// Kernel 1b: reduce the 4 partial slots + fold weights/biases AND the
// residual identity (kv' = kv + I) into the FINAL fp32 kvF[bh][d][e].
// (R12 verbatim)
// ---------------------------------------------------------------------------
__global__ __launch_bounds__(256, 4)
void k_red(const float* __restrict__ Pws,
           const float* __restrict__ kw, const float* __restrict__ kb,
           const float* __restrict__ vw, const float* __restrict__ vb,
           float* __restrict__ kvF)
{
    const int bh  = blockIdx.x;       // 0..255
    const int h   = bh & 7;
    const int tid = threadIdx.x;
    const int d   = tid >> 3;         // 0..31
    const int e0  = (tid & 7) * 4;    // 0,4,..,28

    const float* P0 = Pws + (size_t)(bh * 4 + 0) * SLOT_;
    const float* P1 = Pws + (size_t)(bh * 4 + 1) * SLOT_;
    const float* P2 = Pws + (size_t)(bh * 4 + 2) * SLOT_;
    const float* P3 = Pws + (size_t)(bh * 4 + 3) * SLOT_;
    const float invN = 1.f / (float)N_;

    const float4 s0 = *reinterpret_cast<const float4*>(P0 + d * D_ + e0);
    const float4 s1 = *reinterpret_cast<const float4*>(P1 + d * D_ + e0);
    const float4 s2 = *reinterpret_cast<const float4*>(P2 + d * D_ + e0);
    const float4 s3 = *reinterpret_cast<const float4*>(P3 + d * D_ + e0);
    float Sde[4] = { s0.x + s1.x + s2.x + s3.x, s0.y + s1.y + s2.y + s3.y,
                     s0.z + s1.z + s2.z + s3.z, s0.w + s1.w + s2.w + s3.w };

    const float Td  = P0[1024 + d] + P1[1024 + d] + P2[1024 + d] + P3[1024 + d];
    const float wkd = kw[h * D_ + d];
    const float bkd = kb[h * D_ + d];

    float4 o;
    float* op = &o.x;
    #pragma unroll
    for (int j = 0; j < 4; ++j) {
        const int e = e0 + j;
        const float Te  = P0[1024 + e] + P1[1024 + e] + P2[1024 + e] + P3[1024 + e];
        const float wve = vw[h * D_ + e];
        const float bve = vb[h * D_ + e];
        float v = invN * (wkd * (wve * Sde[j] + bve * Td) + bkd * wve * Te)
                + bkd * bve;
        if (d == e) v += 1.0f;                 // residual folded into kv'
        op[j] = v;
    }
    *reinterpret_cast<float4*>(kvF + (size_t)bh * 1024 + d * D_ + e0) = o;
}

// ---------------------------------------------------------------------------
// Kernel 2: out[n] = x[n] · kv'  (residual inside kv'), ROW-WAVE decomposition.
// Wave = one row at a time; LANE = 4 columns of its head; kv' columns held in
// 128 VGPRs, loaded ONCE (loop-invariant). Per row per wave: 8 broadcast
// global q-loads + 128 v_fma + ONE contiguous 1 KB row store. NO LDS, NO
// barriers; 2-row register ping-pong; 32 consecutive same-batch rows/wave.
// Fixes R12's LDS-issue bound (4.2M -> 0 LDS instrs) and R9's scattered
// stores (16B x 16 rows -> 1 KB x 1 row per instruction).
// ---------------------------------------------------------------------------
__global__ __launch_bounds__(256, 2)
void k2_out(const float* __restrict__ x, const float* __restrict__ kvF,
            float* __restrict__ out)
{
    const int tid  = threadIdx.x;
    const int lane = tid & 63;
    const int wid  = blockIdx.x * 4 + (tid >> 6);
    const int row0 = wid * 32;               // 32 consecutive rows (one batch)
    const int b    = row0 >> 12;             // batch index (4096 rows/batch)
    const int h    = lane >> 3;              // lane's head
    const int e0   = (lane & 7) * 4;         // col-in-head; global col = lane*4

    // kv' columns e0..e0+3 for head h: 32 x f32x4 = 128 VGPR, loop-invariant
    f32x4 kvc[32];
    {
        const float* kvp = kvF + ((size_t)(b * 8 + h)) * 1024 + e0;
        #pragma unroll
        for (int d = 0; d < 32; ++d)
            kvc[d] = *reinterpret_cast<const f32x4*>(kvp + d * 32);
    }

    const float* xq  = x  + (size_t)row0 * C_ + h * 32;   // lane's head slice
    float*       og  = out + (size_t)row0 * C_ + lane * 4;

    float4 qA[8], qB[8];
    #pragma unroll
    for (int c = 0; c < 8; ++c)
        qA[c] = *reinterpret_cast<const float4*>(xq + c * 4);

#define DOT(Q, acc)                                                           \
    {                                                                         \
        acc = (f32x4){0.f, 0.f, 0.f, 0.f};                                    \
        _Pragma("unroll")                                                     \
        for (int c = 0; c < 8; ++c) {                                         \
            const float4 q = Q[c];                                            \
            acc += q.x * kvc[c * 4 + 0];                                      \
            acc += q.y * kvc[c * 4 + 1];                                      \
            acc += q.z * kvc[c * 4 + 2];                                      \
            acc += q.w * kvc[c * 4 + 3];                                      \
        }                                                                     \
    }

    #pragma unroll 4
    for (int r = 0; r < 32; r += 2) {
        // prefetch row r+1 before consuming row r
        if (r + 1 < 32) {
            const float* p = xq + (size_t)(r + 1) * C_;
            #pragma unroll
            for (int c = 0; c < 8; ++c)
                qB[c] = *reinterpret_cast<const float4*>(p + c * 4);
        }
        f32x4 accA;
        DOT(qA, accA)
        *reinterpret_cast<f32x4*>(og + (size_t)r * C_) = accA;

        // prefetch row r+2 before consuming row r+1
        if (r + 2 < 32) {
            const float* p = xq + (size_t)(r + 2) * C_;
            #pragma unroll
            for (int c = 0; c < 8; ++c)
                qA[c] = *reinterpret_cast<const float4*>(p + c * 4);
        }
        f32x4 accB;
        DOT(qB, accB)
        *reinterpret_cast<f32x4*>(og + (size_t)(r + 1) * C_) = accB;
    }
#undef DOT
}

extern "C" void kernel_launch(void* const* d_in, const int* in_sizes, int n_in,
                              void* d_out, int out_size, void* d_ws, size_t ws_size,
                              hipStream_t stream)
{
    const float* x  = (const float*)d_in[0];
    const float* kw = (const float*)d_in[1];
    const float* kb = (const float*)d_in[2];
    const float* vw = (const float*)d_in[3];
    const float* vb = (const float*)d_in[4];
    float* outp = (float*)d_out;

    float* Pws = (float*)d_ws;                       // 1024 x 1088 floats (4.46 MB)
    float* kvF = Pws + (size_t)1024 * SLOT_;         // 256 x 1024 floats (1 MB)

    k1_skv<<<dim3(B_ * H_ * 4), dim3(256), 0, stream>>>(x, Pws);
    k_red<<<dim3(B_ * H_), dim3(256), 0, stream>>>(Pws, kw, kb, vw, vb, kvF);
    // B*N/32 rows-per-wave / 4 waves-per-block = 1024 blocks
    k2_out<<<dim3(B_ * N_ / 128), dim3(256), 0, stream>>>(x, kvF, outp);
}